// Round 3
// baseline (49.517 us; speedup 1.0000x reference)
//
#include <hip/hip_runtime.h>

// GMP: y[b,s] = sum_{l=0}^{9} C_l(b,s) * x[b,s-l], zero for s < 20.
// C_l = sum_{k=0}^{3} a[k, 9-l] |x[s-l]|^k
//     + sum_{m=0}^{9} sum_{k=1}^{4} b[k-1,l,m] |x[s-l-1-m]|^k
// All fp32. Input c unused by the reference.
//
// Round-3 structure: LDS coefficient broadcast (k-contiguous float4) +
// LDS x tile, with T=4 consecutive samples per thread so each float4
// coefficient read feeds 16 FMAs (amortizes the LDS issue cost 4x) and
// the 23-sample |x|-power window lives in registers, shared across the
// 4 samples. All array indexing compile-time constant (full unroll).

constexpr int Kp = 4;
constexpr int Lp = 10;
constexpr int Mp = 10;
constexpr int Dp = Lp + Mp;        // 20
constexpr int BLK = 256;
constexpr int T = 4;               // samples per thread
constexpr int TILE = BLK * T;      // 1024 samples per block
constexpr int HALO = Dp - 1;       // 19
constexpr int W = HALO + T;        // 23-sample register window per thread
constexpr int S_FIXED = 16384;

__global__ __launch_bounds__(BLK, 2) void gmp_kernel(
    const float* __restrict__ x,   // (B, S, 2)
    const float* __restrict__ a,   // (K, L)
    const float* __restrict__ b,   // (K, L, M)
    float* __restrict__ out,       // (B, S, 2)
    int S)
{
    __shared__ float2 sx[TILE + HALO + 1];   // sx[i] = x[s0 - HALO + i], i in [0,1042]
    __shared__ float  sa[Lp][4];             // sa[l][k] = a[k, Lp-1-l]
    __shared__ float  sb[Lp * Mp][4];        // sb[l*Mp+m][k] = b[k, l, m]

    const int t = threadIdx.x;
    const int blocksPerRow = S / TILE;       // 16
    const int brow = blockIdx.x / blocksPerRow;
    const int s0   = (blockIdx.x % blocksPerRow) * TILE;

    // stage coefficients (k contiguous -> one ds_read_b128 per (l[,m]))
    if (t < Lp) {
        #pragma unroll
        for (int k = 0; k < Kp; ++k) sa[t][k] = a[k * Lp + (Lp - 1 - t)];
    }
    if (t >= 64 && t < 64 + Lp * Mp) {
        const int lm = t - 64;
        #pragma unroll
        for (int k = 0; k < Kp; ++k) sb[lm][k] = b[k * Lp * Mp + lm];
    }

    // stage x tile with left halo
    const float2* __restrict__ xrow =
        reinterpret_cast<const float2*>(x) + (size_t)brow * S;
    for (int i = t; i < TILE + HALO; i += BLK) {
        const int s = s0 - HALO + i;
        sx[i] = (s >= 0) ? xrow[s] : make_float2(0.f, 0.f);
    }
    __syncthreads();

    // thread's local base: samples s0+lt .. s0+lt+3; tile index of sample
    // (s0+lt+j) - d  is  lt + HALO + j - d.
    const int lt = t * T;                    // even -> float4-aligned tile reads

    // read 24 float2 (12 x ds_read_b128) covering window [lt, lt+23]
    float2 w[W + 1];
    {
        const float4* sx4 = reinterpret_cast<const float4*>(sx);
        #pragma unroll
        for (int n = 0; n < 12; ++n) {
            const float4 f = sx4[lt / 2 + n];
            w[2 * n]     = make_float2(f.x, f.y);
            w[2 * n + 1] = make_float2(f.z, f.w);
        }
    }

    // powers of |x| over the window; re/im kept for tap indices 10..22
    float q1[W], q2[W], q3[W], q4[W];
    float rex[13], imx[13];
    #pragma unroll
    for (int i = 0; i < W; ++i) {
        const float2 v = w[i];
        const float m2 = v.x * v.x + v.y * v.y;
        const float r  = __builtin_amdgcn_sqrtf(m2);
        q1[i] = r;
        q2[i] = m2;
        q3[i] = m2 * r;
        q4[i] = m2 * m2;
        if (i >= 10) { rex[i - 10] = v.x; imx[i - 10] = v.y; }
    }

    float yr[T] = {0.f, 0.f, 0.f, 0.f};
    float yi[T] = {0.f, 0.f, 0.f, 0.f};

    #pragma unroll
    for (int l = 0; l < Lp; ++l) {
        const float4 ac = *reinterpret_cast<const float4*>(sa[l]);
        float C[T];
        #pragma unroll
        for (int j = 0; j < T; ++j) {
            const int i = HALO + j - l;                     // 19+j-l
            C[j] = ac.x + ac.y * q1[i] + ac.z * q2[i] + ac.w * q3[i];
        }
        #pragma unroll
        for (int m = 0; m < Mp; ++m) {
            const float4 bc = *reinterpret_cast<const float4*>(sb[l * Mp + m]);
            #pragma unroll
            for (int j = 0; j < T; ++j) {
                const int i = HALO - 1 + j - l - m;         // 18+j-l-m
                C[j] += bc.x * q1[i] + bc.y * q2[i]
                      + bc.z * q3[i] + bc.w * q4[i];
            }
        }
        #pragma unroll
        for (int j = 0; j < T; ++j) {
            const int r = 9 + j - l;                        // rex/imx index
            yr[j] += C[j] * rex[r];
            yi[j] += C[j] * imx[r];
        }
    }

    // masked store: 4 consecutive float2 = 2 float4 stores
    float4 o01, o23;
    {
        const int sbase = s0 + lt;
        const bool k0 = (sbase + 0) >= Dp, k1 = (sbase + 1) >= Dp;
        const bool k2 = (sbase + 2) >= Dp, k3 = (sbase + 3) >= Dp;
        o01 = make_float4(k0 ? yr[0] : 0.f, k0 ? yi[0] : 0.f,
                          k1 ? yr[1] : 0.f, k1 ? yi[1] : 0.f);
        o23 = make_float4(k2 ? yr[2] : 0.f, k2 ? yi[2] : 0.f,
                          k3 ? yr[3] : 0.f, k3 ? yi[3] : 0.f);
    }
    float4* o4 = reinterpret_cast<float4*>(out) + ((size_t)brow * S + s0 + lt) / 2;
    o4[0] = o01;
    o4[1] = o23;
}

extern "C" void kernel_launch(void* const* d_in, const int* in_sizes, int n_in,
                              void* d_out, int out_size, void* d_ws, size_t ws_size,
                              hipStream_t stream) {
    const float* x = (const float*)d_in[0];
    const float* a = (const float*)d_in[1];
    const float* b = (const float*)d_in[2];
    // d_in[3] (c) is unused by the reference.
    float* out = (float*)d_out;

    const int S = S_FIXED;
    const int B = in_sizes[0] / (2 * S);
    const int nblocks = B * (S / TILE);

    gmp_kernel<<<dim3(nblocks), dim3(BLK), 0, stream>>>(x, a, b, out, S);
}